// Round 1
// baseline (1370.601 us; speedup 1.0000x reference)
//
#include <hip/hip_runtime.h>
#include <stdint.h>

typedef unsigned short u16;
typedef __attribute__((ext_vector_type(8))) short bf16x8;       // 8 bf16 = 4 VGPR (MFMA A/B frag)
typedef __attribute__((ext_vector_type(4))) float f32x4;        // MFMA C/D frag
typedef __attribute__((ext_vector_type(8))) unsigned short us8; // 16B bf16 store
typedef __attribute__((ext_vector_type(4))) float fvec4;

#define BATCH 2
#define SEQ   2048
#define DIMM  2048
#define NH    16
#define DH    128
#define ROWS  (BATCH*SEQ)   // 4096
#define QKVN  (DIMM + DH)   // 2176
#define FFH   8192          // FF_MULT*DIM
#define LOG2E 1.44269504088896340736f

static __device__ __forceinline__ u16 f2bf(float x) {
  union { float f; uint32_t u; } v; v.f = x;
  uint32_t r = (v.u + 0x7fffu + ((v.u >> 16) & 1u)) >> 16;
  return (u16)r;
}

// async 16B global->LDS (dest = wave-uniform base + lane*16)
static __device__ __forceinline__ void gld_lds16(const void* g, void* l) {
  __builtin_amdgcn_global_load_lds(
      (const __attribute__((address_space(1))) uint32_t*)g,
      (__attribute__((address_space(3))) uint32_t*)l, 16, 0, 0);
}

// ---------------- RMSNorm: x fp32 -> xn bf16 ----------------
__global__ __launch_bounds__(256)
void rmsnorm_k(const float* __restrict__ x, const float* __restrict__ g, u16* __restrict__ xn) {
  const int row = blockIdx.x;
  const float* xr = x + (size_t)row * DIMM;
  const int off = threadIdx.x * 8;
  fvec4 a = *(const fvec4*)(xr + off);
  fvec4 b = *(const fvec4*)(xr + off + 4);
  float ss = a[0]*a[0]+a[1]*a[1]+a[2]*a[2]+a[3]*a[3]
           + b[0]*b[0]+b[1]*b[1]+b[2]*b[2]+b[3]*b[3];
  #pragma unroll
  for (int m = 32; m >= 1; m >>= 1) ss += __shfl_xor(ss, m);
  __shared__ float red[4];
  if ((threadIdx.x & 63) == 0) red[threadIdx.x >> 6] = ss;
  __syncthreads();
  float tot = red[0] + red[1] + red[2] + red[3];
  float inv = 1.0f / fmaxf(sqrtf(tot * (1.0f / DIMM)), 1e-8f);
  fvec4 ga = *(const fvec4*)(g + off);
  fvec4 gb = *(const fvec4*)(g + off + 4);
  us8 o;
  #pragma unroll
  for (int i = 0; i < 4; i++) { o[i] = f2bf(a[i]*inv*ga[i]); o[4+i] = f2bf(b[i]*inv*gb[i]); }
  *(us8*)(xn + (size_t)row * DIMM + off) = o;
}

// ---------------- transpose (+cast to bf16): in R x C -> out C x R ----------------
template<typename TIN>
__global__ __launch_bounds__(256)
void transpose_to_bf16(const TIN* __restrict__ in, u16* __restrict__ out, int R, int C) {
  __shared__ u16 tile[64 * 65];
  const int r0 = blockIdx.y * 64, c0 = blockIdx.x * 64;
  const int tr = threadIdx.x >> 2;
  const int tc = (threadIdx.x & 3) * 16;
  const TIN* ip = in + (size_t)(r0 + tr) * C + c0 + tc;
  u16 tmp[16];
  #pragma unroll
  for (int i = 0; i < 16; i++) {
    if constexpr (sizeof(TIN) == 4) tmp[i] = f2bf(((const float*)ip)[i]);
    else                            tmp[i] = ((const u16*)ip)[i];
  }
  #pragma unroll
  for (int i = 0; i < 16; i++) tile[tr * 65 + tc + i] = tmp[i];
  __syncthreads();
  const int oc  = c0 + tr;
  const int orr = (threadIdx.x & 3) * 16;
  us8 v0, v1;
  #pragma unroll
  for (int i = 0; i < 8; i++) v0[i] = tile[(orr + i) * 65 + tr];
  #pragma unroll
  for (int i = 0; i < 8; i++) v1[i] = tile[(orr + 8 + i) * 65 + tr];
  u16* op = out + (size_t)oc * R + r0 + orr;
  *(us8*)op = v0;
  *(us8*)(op + 8) = v1;
}

// ---------------- generic 128x128 bf16 GEMM, BK=32, global_load_lds + XOR swizzle ----------------
// A: M x K bf16 row-major. BT: N x K bf16 row-major (pre-transposed weights).
// MODE 0: qkv split -> q bf16 (ld DIMM) / kv bf16 (ld DH). MODE 2: f32 store. MODE 3: f32 add.
template<int MODE>
__global__ __launch_bounds__(256, 2)
void gemm_bf16(const u16* __restrict__ A, const u16* __restrict__ BT, int K,
               float* __restrict__ outF, u16* __restrict__ outQ, u16* __restrict__ outKV) {
  __shared__ __align__(16) u16 lA[128 * 32];
  __shared__ __align__(16) u16 lB[128 * 32];
  const int tid = threadIdx.x;
  const int wave = tid >> 6, lane = tid & 63;
  const int lid = lane & 15, quad = lane >> 4;
  const int wm = wave >> 1, wn = wave & 1;
  const int row0 = blockIdx.y * 128;
  const int col0 = blockIdx.x * 128;
  f32x4 acc[4][4];
  #pragma unroll
  for (int i = 0; i < 4; i++)
    #pragma unroll
    for (int j = 0; j < 4; j++) { acc[i][j][0]=0.f; acc[i][j][1]=0.f; acc[i][j][2]=0.f; acc[i][j][3]=0.f; }

  const int rA0 = wave * 32;
  const int rsub = lane >> 2;        // 0..15 within a 16-row staging instr
  const int cl = lane & 3;           // chunk slot 0..3

  for (int k0 = 0; k0 < K; k0 += 32) {
    #pragma unroll
    for (int h2 = 0; h2 < 2; ++h2) {
      int rloc = rA0 + h2 * 16 + rsub;
      int gc = cl ^ ((rloc >> 1) & 3);                 // source k-chunk for this LDS slot
      gld_lds16(A  + (size_t)(row0 + rloc) * K + k0 + gc * 8, lA + (rA0 + h2 * 16) * 32);
      gld_lds16(BT + (size_t)(col0 + rloc) * K + k0 + gc * 8, lB + (rA0 + h2 * 16) * 32);
    }
    __syncthreads();
    bf16x8 af[4], bfr[4];
    #pragma unroll
    for (int i = 0; i < 4; i++) {
      int r  = wm * 64 + i * 16 + lid;
      af[i]  = *(const bf16x8*)(lA + r * 32 + (quad ^ ((r >> 1) & 3)) * 8);
      int rb = wn * 64 + i * 16 + lid;
      bfr[i] = *(const bf16x8*)(lB + rb * 32 + (quad ^ ((rb >> 1) & 3)) * 8);
    }
    #pragma unroll
    for (int im = 0; im < 4; im++)
      #pragma unroll
      for (int in = 0; in < 4; in++)
        acc[im][in] = __builtin_amdgcn_mfma_f32_16x16x32_bf16(af[im], bfr[in], acc[im][in], 0, 0, 0);
    __syncthreads();
  }

  #pragma unroll
  for (int im = 0; im < 4; im++)
    #pragma unroll
    for (int in = 0; in < 4; in++) {
      int col = col0 + wn * 64 + in * 16 + lid;
      int rbase = row0 + wm * 64 + im * 16 + quad * 4;
      #pragma unroll
      for (int rg = 0; rg < 4; rg++) {
        float v = acc[im][in][rg];
        int row = rbase + rg;
        if constexpr (MODE == 0) {
          if (col < DIMM) outQ[(size_t)row * DIMM + col] = f2bf(v);
          else            outKV[(size_t)row * DH + (col - DIMM)] = f2bf(v);
        } else if constexpr (MODE == 2) {
          outF[(size_t)row * DIMM + col] = v;
        } else {
          outF[(size_t)row * DIMM + col] += v;
        }
      }
    }
}

// ---------------- ff1 GEMM fused with SwiGLU: block = 128 rows x (64 val + 64 gate cols) ----------------
__global__ __launch_bounds__(256, 2)
void gemm_ff1_swiglu(const u16* __restrict__ A, const u16* __restrict__ BT, u16* __restrict__ FF) {
  __shared__ __align__(16) u16 lA[128 * 32];
  __shared__ __align__(16) u16 lB[128 * 32];   // rows 0..63 = val strip, 64..127 = gate strip
  const int tid = threadIdx.x;
  const int wave = tid >> 6, lane = tid & 63;
  const int lid = lane & 15, quad = lane >> 4;
  const int wm = wave >> 1, wn = wave & 1;
  const int row0 = blockIdx.y * 128;
  const int n0 = blockIdx.x * 64;
  const int K = DIMM;
  f32x4 av[4][2], ag[4][2];
  #pragma unroll
  for (int i = 0; i < 4; i++)
    #pragma unroll
    for (int j = 0; j < 2; j++) {
      av[i][j][0]=0.f; av[i][j][1]=0.f; av[i][j][2]=0.f; av[i][j][3]=0.f;
      ag[i][j][0]=0.f; ag[i][j][1]=0.f; ag[i][j][2]=0.f; ag[i][j][3]=0.f;
    }
  const int rA0 = wave * 32;
  const int rsub = lane >> 2, cl = lane & 3;

  for (int k0 = 0; k0 < K; k0 += 32) {
    #pragma unroll
    for (int h2 = 0; h2 < 2; ++h2) {
      int rloc = rA0 + h2 * 16 + rsub;
      int gc = cl ^ ((rloc >> 1) & 3);
      int grow = (rloc < 64) ? (n0 + rloc) : (FFH + n0 + rloc - 64);
      gld_lds16(A  + (size_t)(row0 + rloc) * K + k0 + gc * 8, lA + (rA0 + h2 * 16) * 32);
      gld_lds16(BT + (size_t)grow * K + k0 + gc * 8,          lB + (rA0 + h2 * 16) * 32);
    }
    __syncthreads();
    bf16x8 af[4], bv[2], bg[2];
    #pragma unroll
    for (int i = 0; i < 4; i++) {
      int r = wm * 64 + i * 16 + lid;
      af[i] = *(const bf16x8*)(lA + r * 32 + (quad ^ ((r >> 1) & 3)) * 8);
    }
    #pragma unroll
    for (int i = 0; i < 2; i++) {
      int rv = wn * 32 + i * 16 + lid;
      bv[i] = *(const bf16x8*)(lB + rv * 32 + (quad ^ ((rv >> 1) & 3)) * 8);
      int rg2 = 64 + wn * 32 + i * 16 + lid;
      bg[i] = *(const bf16x8*)(lB + rg2 * 32 + (quad ^ ((rg2 >> 1) & 3)) * 8);
    }
    #pragma unroll
    for (int im = 0; im < 4; im++)
      #pragma unroll
      for (int in = 0; in < 2; in++) {
        av[im][in] = __builtin_amdgcn_mfma_f32_16x16x32_bf16(af[im], bv[in], av[im][in], 0, 0, 0);
        ag[im][in] = __builtin_amdgcn_mfma_f32_16x16x32_bf16(af[im], bg[in], ag[im][in], 0, 0, 0);
      }
    __syncthreads();
  }

  #pragma unroll
  for (int im = 0; im < 4; im++)
    #pragma unroll
    for (int in = 0; in < 2; in++) {
      int col = n0 + wn * 32 + in * 16 + lid;
      int rbase = row0 + wm * 64 + im * 16 + quad * 4;
      #pragma unroll
      for (int rg = 0; rg < 4; rg++) {
        float vv = av[im][in][rg];
        float gg = ag[im][in][rg];
        float sig = 1.0f / (1.0f + exp2f(-gg * LOG2E));   // sigmoid(gg)
        FF[(size_t)(rbase + rg) * FFH + col] = f2bf(vv * gg * sig);
      }
    }
}

// ---------------- flash attention: MQA, ALiBi, causal. 16 q-rows per wave, 64-col kv tiles ----------------
__global__ __launch_bounds__(256, 2)
void attn_k(const u16* __restrict__ qws, const u16* __restrict__ kvws,
            const u16* __restrict__ kvt, u16* __restrict__ attnws) {
  __shared__ __align__(16) u16 plds[4][16][88];   // per-wave P transpose buffer (stride 88 -> 2-way only)
  const int wave = threadIdx.x >> 6, lane = threadIdx.x & 63;
  const int lid = lane & 15, quad = lane >> 4;
  const int h = blockIdx.y, b = blockIdx.z;
  const int r0 = blockIdx.x * 64 + wave * 16;
  const float slope = exp2f(-0.5f * (float)(h + 1));   // ALiBi, HEADS=16 (pow2)
  const float scale = 0.08838834764831845f;            // 1/sqrt(128)
  const float NEG = -__builtin_inff();

  const u16* qp = qws + ((size_t)(b * SEQ + r0 + lid)) * DIMM + h * DH;
  bf16x8 qf[4];
  #pragma unroll
  for (int ks = 0; ks < 4; ks++) qf[ks] = *(const bf16x8*)(qp + ks * 32 + quad * 8);

  f32x4 o[8];
  #pragma unroll
  for (int i = 0; i < 8; i++) { o[i][0]=0.f; o[i][1]=0.f; o[i][2]=0.f; o[i][3]=0.f; }
  float m_i[4] = {NEG, NEG, NEG, NEG};
  float l_i[4] = {0.f, 0.f, 0.f, 0.f};

  const u16* kvb = kvws + (size_t)b * SEQ * DH;
  const u16* kvtb = kvt + (size_t)b * DH * SEQ;

  for (int j0 = 0; j0 <= r0 + 15; j0 += 64) {
    // S = Q * KV^T  (16 x 64)
    f32x4 s[4];
    #pragma unroll
    for (int nb = 0; nb < 4; nb++) { s[nb][0]=0.f; s[nb][1]=0.f; s[nb][2]=0.f; s[nb][3]=0.f; }
    #pragma unroll
    for (int nb = 0; nb < 4; nb++) {
      const u16* kp = kvb + (size_t)(j0 + nb * 16 + lid) * DH + quad * 8;
      #pragma unroll
      for (int ks = 0; ks < 4; ks++)
        s[nb] = __builtin_amdgcn_mfma_f32_16x16x32_bf16(qf[ks], *(const bf16x8*)(kp + ks * 32), s[nb], 0, 0, 0);
    }
    // scale + ALiBi + causal mask, tile row-max
    float pv[4][4];
    float mt[4] = {NEG, NEG, NEG, NEG};
    #pragma unroll
    for (int nb = 0; nb < 4; nb++)
      #pragma unroll
      for (int rg = 0; rg < 4; rg++) {
        int row = r0 + quad * 4 + rg;
        int j = j0 + nb * 16 + lid;
        float v = (j <= row) ? (s[nb][rg] * scale - slope * (float)(row - j)) : NEG;
        pv[nb][rg] = v;
        mt[rg] = fmaxf(mt[rg], v);
      }
    #pragma unroll
    for (int rg = 0; rg < 4; rg++) {
      #pragma unroll
      for (int msk = 1; msk < 16; msk <<= 1) mt[rg] = fmaxf(mt[rg], __shfl_xor(mt[rg], msk));
    }
    float alpha[4];
    #pragma unroll
    for (int rg = 0; rg < 4; rg++) {
      float mn = fmaxf(m_i[rg], mt[rg]);
      alpha[rg] = exp2f((m_i[rg] - mn) * LOG2E);   // m_i=-inf on first tile -> 0
      m_i[rg] = mn;
    }
    float rs[4] = {0.f, 0.f, 0.f, 0.f};
    #pragma unroll
    for (int nb = 0; nb < 4; nb++)
      #pragma unroll
      for (int rg = 0; rg < 4; rg++) {
        float p = exp2f((pv[nb][rg] - m_i[rg]) * LOG2E);
        pv[nb][rg] = p;
        rs[rg] += p;
      }
    #pragma unroll
    for (int rg = 0; rg < 4; rg++) {
      #pragma unroll
      for (int msk = 1; msk < 16; msk <<= 1) rs[rg] += __shfl_xor(rs[rg], msk);
      l_i[rg] = l_i[rg] * alpha[rg] + rs[rg];
    }
    #pragma unroll
    for (int i = 0; i < 8; i++)
      #pragma unroll
      for (int rg = 0; rg < 4; rg++) o[i][rg] *= alpha[rg];
    // P (C-layout) -> LDS -> A-layout
    #pragma unroll
    for (int nb = 0; nb < 4; nb++)
      #pragma unroll
      for (int rg = 0; rg < 4; rg++)
        plds[wave][quad * 4 + rg][nb * 16 + lid] = f2bf(pv[nb][rg]);
    asm volatile("s_waitcnt lgkmcnt(0)" ::: "memory");
    // O += P * KV
    #pragma unroll
    for (int ks2 = 0; ks2 < 2; ks2++) {
      bf16x8 pa = *(const bf16x8*)&plds[wave][lid][ks2 * 32 + quad * 8];
      #pragma unroll
      for (int nd = 0; nd < 8; nd++) {
        const u16* vp = kvtb + (size_t)(nd * 16 + lid) * SEQ + j0 + ks2 * 32 + quad * 8;
        o[nd] = __builtin_amdgcn_mfma_f32_16x16x32_bf16(pa, *(const bf16x8*)vp, o[nd], 0, 0, 0);
      }
    }
  }
  #pragma unroll
  for (int nd = 0; nd < 8; nd++)
    #pragma unroll
    for (int rg = 0; rg < 4; rg++) {
      int row = r0 + quad * 4 + rg;
      attnws[((size_t)(b * SEQ + row)) * DIMM + h * DH + nd * 16 + lid] = f2bf(o[nd][rg] * (1.0f / l_i[rg]));
    }
}

// ---------------- launcher ----------------
extern "C" void kernel_launch(void* const* d_in, const int* in_sizes, int n_in,
                              void* d_out, int out_size, void* d_ws, size_t ws_size,
                              hipStream_t stream) {
  (void)in_sizes; (void)n_in; (void)out_size; (void)ws_size;
  const float* x     = (const float*)d_in[0];
  const float* g     = (const float*)d_in[1];
  const float* w_qkv = (const float*)d_in[2];
  const float* w_ao  = (const float*)d_in[3];
  const float* w_ff1 = (const float*)d_in[4];
  const float* w_ff2 = (const float*)d_in[5];
  float* out = (float*)d_out;

  u16* ws = (u16*)d_ws;
  u16* xn     = ws;                   // 4096x2048
  u16* wTqkv  = xn     + 8388608;     // 2176x2048
  u16* wTattn = wTqkv  + 4456448;     // 2048x2048
  u16* wTff1  = wTattn + 4194304;     // 16384x2048
  u16* wTff2  = wTff1  + 33554432;    // 2048x8192
  u16* ffin   = wTff2  + 16777216;    // 4096x8192
  u16* qws    = ffin   + 33554432;    // 4096x2048
  u16* kvws   = qws    + 8388608;     // 4096x128
  u16* kvtws  = kvws   + 524288;      // 2 x (128x2048)
  u16* attnws = kvtws  + 524288;      // 4096x2048

  // weight transposes (fp32 -> bf16, N x K)
  transpose_to_bf16<float><<<dim3(QKVN/64, DIMM/64), 256, 0, stream>>>(w_qkv, wTqkv, DIMM, QKVN);
  transpose_to_bf16<float><<<dim3(DIMM/64, DIMM/64), 256, 0, stream>>>(w_ao, wTattn, DIMM, DIMM);
  transpose_to_bf16<float><<<dim3((2*FFH)/64, DIMM/64), 256, 0, stream>>>(w_ff1, wTff1, DIMM, 2*FFH);
  transpose_to_bf16<float><<<dim3(DIMM/64, FFH/64), 256, 0, stream>>>(w_ff2, wTff2, FFH, DIMM);

  rmsnorm_k<<<ROWS, 256, 0, stream>>>(x, g, xn);

  // qkv projection (split epilogue)
  gemm_bf16<0><<<dim3(QKVN/128, ROWS/128), 256, 0, stream>>>(xn, wTqkv, DIMM, nullptr, qws, kvws);

  // kv -> kvT per batch
  transpose_to_bf16<u16><<<dim3(DH/64, SEQ/64), 256, 0, stream>>>(kvws, kvtws, SEQ, DH);
  transpose_to_bf16<u16><<<dim3(DH/64, SEQ/64), 256, 0, stream>>>(kvws + (size_t)SEQ*DH, kvtws + (size_t)DH*SEQ, SEQ, DH);

  attn_k<<<dim3(SEQ/64, NH, BATCH), 256, 0, stream>>>(qws, kvws, kvtws, attnws);

  // FF path
  gemm_ff1_swiglu<<<dim3(FFH/64, ROWS/128), 256, 0, stream>>>(xn, wTff1, ffin);
  gemm_bf16<2><<<dim3(DIMM/128, ROWS/128), 256, 0, stream>>>(ffin, wTff2, FFH, out, nullptr, nullptr);

  // attention out-projection, accumulate into d_out
  gemm_bf16<3><<<dim3(DIMM/128, ROWS/128), 256, 0, stream>>>(attnws, wTattn, DIMM, out, nullptr, nullptr);
}

// Round 2
// 1034.257 us; speedup vs baseline: 1.3252x; 1.3252x over previous
//
#include <hip/hip_runtime.h>
#include <stdint.h>

typedef unsigned short u16;
typedef __attribute__((ext_vector_type(8))) short bf16x8;       // 8 bf16 = 4 VGPR (MFMA A/B frag)
typedef __attribute__((ext_vector_type(4))) float f32x4;        // MFMA C/D frag
typedef __attribute__((ext_vector_type(8))) unsigned short us8; // 16B bf16 store
typedef __attribute__((ext_vector_type(4))) float fvec4;

#define BATCH 2
#define SEQ   2048
#define DIMM  2048
#define NH    16
#define DH    128
#define ROWS  (BATCH*SEQ)   // 4096
#define QKVN  (DIMM + DH)   // 2176
#define FFH   8192          // FF_MULT*DIM
#define LOG2E 1.44269504088896340736f

static __device__ __forceinline__ u16 f2bf(float x) {
  union { float f; uint32_t u; } v; v.f = x;
  uint32_t r = (v.u + 0x7fffu + ((v.u >> 16) & 1u)) >> 16;
  return (u16)r;
}

static __device__ __forceinline__ float fast_exp2(float x) {
  float r; asm("v_exp_f32 %0, %1" : "=v"(r) : "v"(x)); return r;
}

// async 16B global->LDS (dest = wave-uniform base + lane*16)
static __device__ __forceinline__ void gld_lds16(const void* g, void* l) {
  __builtin_amdgcn_global_load_lds(
      (const __attribute__((address_space(1))) uint32_t*)g,
      (__attribute__((address_space(3))) uint32_t*)l, 16, 0, 0);
}

// ---------------- RMSNorm: x fp32 -> xn bf16 ----------------
__global__ __launch_bounds__(256)
void rmsnorm_k(const float* __restrict__ x, const float* __restrict__ g, u16* __restrict__ xn) {
  const int row = blockIdx.x;
  const float* xr = x + (size_t)row * DIMM;
  const int off = threadIdx.x * 8;
  fvec4 a = *(const fvec4*)(xr + off);
  fvec4 b = *(const fvec4*)(xr + off + 4);
  float ss = a[0]*a[0]+a[1]*a[1]+a[2]*a[2]+a[3]*a[3]
           + b[0]*b[0]+b[1]*b[1]+b[2]*b[2]+b[3]*b[3];
  #pragma unroll
  for (int m = 32; m >= 1; m >>= 1) ss += __shfl_xor(ss, m);
  __shared__ float red[4];
  if ((threadIdx.x & 63) == 0) red[threadIdx.x >> 6] = ss;
  __syncthreads();
  float tot = red[0] + red[1] + red[2] + red[3];
  float inv = 1.0f / fmaxf(sqrtf(tot * (1.0f / DIMM)), 1e-8f);
  fvec4 ga = *(const fvec4*)(g + off);
  fvec4 gb = *(const fvec4*)(g + off + 4);
  us8 o;
  #pragma unroll
  for (int i = 0; i < 4; i++) { o[i] = f2bf(a[i]*inv*ga[i]); o[4+i] = f2bf(b[i]*inv*gb[i]); }
  *(us8*)(xn + (size_t)row * DIMM + off) = o;
}

// ---------------- transpose (+cast to bf16): in R x C -> out C x R ----------------
template<typename TIN>
__global__ __launch_bounds__(256)
void transpose_to_bf16(const TIN* __restrict__ in, u16* __restrict__ out, int R, int C) {
  __shared__ u16 tile[64 * 65];
  const int r0 = blockIdx.y * 64, c0 = blockIdx.x * 64;
  const int tr = threadIdx.x >> 2;
  const int tc = (threadIdx.x & 3) * 16;
  const TIN* ip = in + (size_t)(r0 + tr) * C + c0 + tc;
  u16 tmp[16];
  #pragma unroll
  for (int i = 0; i < 16; i++) {
    if constexpr (sizeof(TIN) == 4) tmp[i] = f2bf(((const float*)ip)[i]);
    else                            tmp[i] = ((const u16*)ip)[i];
  }
  #pragma unroll
  for (int i = 0; i < 16; i++) tile[tr * 65 + tc + i] = tmp[i];
  __syncthreads();
  const int oc  = c0 + tr;
  const int orr = (threadIdx.x & 3) * 16;
  us8 v0, v1;
  #pragma unroll
  for (int i = 0; i < 8; i++) v0[i] = tile[(orr + i) * 65 + tr];
  #pragma unroll
  for (int i = 0; i < 8; i++) v1[i] = tile[(orr + 8 + i) * 65 + tr];
  u16* op = out + (size_t)oc * R + r0 + orr;
  *(us8*)op = v0;
  *(us8*)(op + 8) = v1;
}

// ---------------- generic 128x128 bf16 GEMM, BK=32, global_load_lds + XOR swizzle ----------------
template<int MODE>
__global__ __launch_bounds__(256, 2)
void gemm_bf16(const u16* __restrict__ A, const u16* __restrict__ BT, int K,
               float* __restrict__ outF, u16* __restrict__ outQ, u16* __restrict__ outKV) {
  __shared__ __align__(16) u16 lA[128 * 32];
  __shared__ __align__(16) u16 lB[128 * 32];
  const int tid = threadIdx.x;
  const int wave = tid >> 6, lane = tid & 63;
  const int lid = lane & 15, quad = lane >> 4;
  const int wm = wave >> 1, wn = wave & 1;
  const int row0 = blockIdx.y * 128;
  const int col0 = blockIdx.x * 128;
  f32x4 acc[4][4];
  #pragma unroll
  for (int i = 0; i < 4; i++)
    #pragma unroll
    for (int j = 0; j < 4; j++) { acc[i][j][0]=0.f; acc[i][j][1]=0.f; acc[i][j][2]=0.f; acc[i][j][3]=0.f; }

  const int rA0 = wave * 32;
  const int rsub = lane >> 2;
  const int cl = lane & 3;

  for (int k0 = 0; k0 < K; k0 += 32) {
    #pragma unroll
    for (int h2 = 0; h2 < 2; ++h2) {
      int rloc = rA0 + h2 * 16 + rsub;
      int gc = cl ^ ((rloc >> 1) & 3);
      gld_lds16(A  + (size_t)(row0 + rloc) * K + k0 + gc * 8, lA + (rA0 + h2 * 16) * 32);
      gld_lds16(BT + (size_t)(col0 + rloc) * K + k0 + gc * 8, lB + (rA0 + h2 * 16) * 32);
    }
    __syncthreads();
    bf16x8 af[4], bfr[4];
    #pragma unroll
    for (int i = 0; i < 4; i++) {
      int r  = wm * 64 + i * 16 + lid;
      af[i]  = *(const bf16x8*)(lA + r * 32 + (quad ^ ((r >> 1) & 3)) * 8);
      int rb = wn * 64 + i * 16 + lid;
      bfr[i] = *(const bf16x8*)(lB + rb * 32 + (quad ^ ((rb >> 1) & 3)) * 8);
    }
    #pragma unroll
    for (int im = 0; im < 4; im++)
      #pragma unroll
      for (int in = 0; in < 4; in++)
        acc[im][in] = __builtin_amdgcn_mfma_f32_16x16x32_bf16(af[im], bfr[in], acc[im][in], 0, 0, 0);
    __syncthreads();
  }

  #pragma unroll
  for (int im = 0; im < 4; im++)
    #pragma unroll
    for (int in = 0; in < 4; in++) {
      int col = col0 + wn * 64 + in * 16 + lid;
      int rbase = row0 + wm * 64 + im * 16 + quad * 4;
      #pragma unroll
      for (int rg = 0; rg < 4; rg++) {
        float v = acc[im][in][rg];
        int row = rbase + rg;
        if constexpr (MODE == 0) {
          if (col < DIMM) outQ[(size_t)row * DIMM + col] = f2bf(v);
          else            outKV[(size_t)row * DH + (col - DIMM)] = f2bf(v);
        } else if constexpr (MODE == 2) {
          outF[(size_t)row * DIMM + col] = v;
        } else {
          outF[(size_t)row * DIMM + col] += v;
        }
      }
    }
}

// ---------------- ff1 GEMM fused with SwiGLU ----------------
__global__ __launch_bounds__(256, 2)
void gemm_ff1_swiglu(const u16* __restrict__ A, const u16* __restrict__ BT, u16* __restrict__ FF) {
  __shared__ __align__(16) u16 lA[128 * 32];
  __shared__ __align__(16) u16 lB[128 * 32];
  const int tid = threadIdx.x;
  const int wave = tid >> 6, lane = tid & 63;
  const int lid = lane & 15, quad = lane >> 4;
  const int wm = wave >> 1, wn = wave & 1;
  const int row0 = blockIdx.y * 128;
  const int n0 = blockIdx.x * 64;
  const int K = DIMM;
  f32x4 av[4][2], ag[4][2];
  #pragma unroll
  for (int i = 0; i < 4; i++)
    #pragma unroll
    for (int j = 0; j < 2; j++) {
      av[i][j][0]=0.f; av[i][j][1]=0.f; av[i][j][2]=0.f; av[i][j][3]=0.f;
      ag[i][j][0]=0.f; ag[i][j][1]=0.f; ag[i][j][2]=0.f; ag[i][j][3]=0.f;
    }
  const int rA0 = wave * 32;
  const int rsub = lane >> 2, cl = lane & 3;

  for (int k0 = 0; k0 < K; k0 += 32) {
    #pragma unroll
    for (int h2 = 0; h2 < 2; ++h2) {
      int rloc = rA0 + h2 * 16 + rsub;
      int gc = cl ^ ((rloc >> 1) & 3);
      int grow = (rloc < 64) ? (n0 + rloc) : (FFH + n0 + rloc - 64);
      gld_lds16(A  + (size_t)(row0 + rloc) * K + k0 + gc * 8, lA + (rA0 + h2 * 16) * 32);
      gld_lds16(BT + (size_t)grow * K + k0 + gc * 8,          lB + (rA0 + h2 * 16) * 32);
    }
    __syncthreads();
    bf16x8 af[4], bv[2], bg[2];
    #pragma unroll
    for (int i = 0; i < 4; i++) {
      int r = wm * 64 + i * 16 + lid;
      af[i] = *(const bf16x8*)(lA + r * 32 + (quad ^ ((r >> 1) & 3)) * 8);
    }
    #pragma unroll
    for (int i = 0; i < 2; i++) {
      int rv = wn * 32 + i * 16 + lid;
      bv[i] = *(const bf16x8*)(lB + rv * 32 + (quad ^ ((rv >> 1) & 3)) * 8);
      int rg2 = 64 + wn * 32 + i * 16 + lid;
      bg[i] = *(const bf16x8*)(lB + rg2 * 32 + (quad ^ ((rg2 >> 1) & 3)) * 8);
    }
    #pragma unroll
    for (int im = 0; im < 4; im++)
      #pragma unroll
      for (int in = 0; in < 2; in++) {
        av[im][in] = __builtin_amdgcn_mfma_f32_16x16x32_bf16(af[im], bv[in], av[im][in], 0, 0, 0);
        ag[im][in] = __builtin_amdgcn_mfma_f32_16x16x32_bf16(af[im], bg[in], ag[im][in], 0, 0, 0);
      }
    __syncthreads();
  }

  #pragma unroll
  for (int im = 0; im < 4; im++)
    #pragma unroll
    for (int in = 0; in < 2; in++) {
      int col = n0 + wn * 32 + in * 16 + lid;
      int rbase = row0 + wm * 64 + im * 16 + quad * 4;
      #pragma unroll
      for (int rg = 0; rg < 4; rg++) {
        float vv = av[im][in][rg];
        float gg = ag[im][in][rg];
        float sig = 1.0f / (1.0f + fast_exp2(-gg * LOG2E));
        FF[(size_t)(rbase + rg) * FFH + col] = f2bf(vv * gg * sig);
      }
    }
}

// ---------------- flash attention v2: LDS-staged KV tiles, paired row-tiles, 32 rows/wave ----------------
// Block: 4 waves x 32 q-rows = 128-row tile; processes tiles T0=pair, T1=15-pair (uniform 17 j-iters).
// j-tile 128 wide; kv[j][d] and kvT[d][j] tiles staged via global_load_lds with XOR chunk swizzle.
__global__ __launch_bounds__(256, 1)
void attn_k2(const u16* __restrict__ qws, const u16* __restrict__ kvws,
             const u16* __restrict__ kvt, u16* __restrict__ attnws) {
  __shared__ __align__(16) u16 kvls[128 * 128];   // 32 KB
  __shared__ __align__(16) u16 kvtls[128 * 128];  // 32 KB
  __shared__ __align__(16) u16 plds[4][32][136];  // 34 KB, stride 136 u16 = 272 B (16B aligned)
  const int tid = threadIdx.x;
  const int wave = tid >> 6, lane = tid & 63;
  const int lid = lane & 15, quad = lane >> 4;
  const int hb = blockIdx.y;
  const int h = hb & (NH - 1), b = hb >> 4;
  const int pair = blockIdx.x;                     // 0..7
  const float slope2 = fast_exp2(-0.5f * (float)(h + 1)) * LOG2E;
  const float scale2 = 0.08838834764831845f * LOG2E;   // 1/sqrt(128) * log2(e)
  const float NEG = -__builtin_inff();

  const u16* kvb  = kvws + (size_t)b * SEQ * DH;
  const u16* kvtb = kvt  + (size_t)b * DH * SEQ;

  #pragma unroll 1
  for (int tt = 0; tt < 2; tt++) {
    const int T = tt ? (15 - pair) : pair;
    const int rw = T * 128 + wave * 32;            // wave's 32-row strip base

    bf16x8 qf[2][4];
    #pragma unroll
    for (int ig = 0; ig < 2; ig++)
      #pragma unroll
      for (int ks = 0; ks < 4; ks++)
        qf[ig][ks] = *(const bf16x8*)(qws + (size_t)(b * SEQ + rw + ig * 16 + lid) * DIMM
                                       + h * DH + ks * 32 + quad * 8);
    float srow2[2][4];
    #pragma unroll
    for (int ig = 0; ig < 2; ig++)
      #pragma unroll
      for (int rg = 0; rg < 4; rg++)
        srow2[ig][rg] = slope2 * (float)(rw + ig * 16 + quad * 4 + rg);

    f32x4 o[2][8];
    #pragma unroll
    for (int ig = 0; ig < 2; ig++)
      #pragma unroll
      for (int nd = 0; nd < 8; nd++) { o[ig][nd][0]=0.f; o[ig][nd][1]=0.f; o[ig][nd][2]=0.f; o[ig][nd][3]=0.f; }
    float m2[2][4], l[2][4];
    #pragma unroll
    for (int ig = 0; ig < 2; ig++)
      #pragma unroll
      for (int rg = 0; rg < 4; rg++) { m2[ig][rg] = NEG; l[ig][rg] = 0.f; }

    const int njt = T + 1;
    #pragma unroll 1
    for (int jt = 0; jt < njt; jt++) {
      const int j0 = jt * 128;
      __syncthreads();                              // prev tile reads complete
      {
        const int c = lane & 15;
        const int r4 = lane >> 4;
        #pragma unroll
        for (int it = 0; it < 8; it++) {
          const int r = wave * 32 + it * 4 + r4;
          const int gc = c ^ (r & 15);
          gld_lds16(kvb  + (size_t)(j0 + r) * DH + gc * 8,        kvls  + (wave * 32 + it * 4) * 128);
          gld_lds16(kvtb + (size_t)r * SEQ + j0 + gc * 8,         kvtls + (wave * 32 + it * 4) * 128);
        }
      }
      __syncthreads();                              // staging drained (vmcnt0)

      const int rhi = rw + 31;
      const int nbmax = min(8, ((rhi - j0) >> 4) + 1);   // wave-uniform
      const int ks2max = (nbmax + 1) >> 1;

      float pvv[2][8][4];
      float mt[2][4];
      #pragma unroll
      for (int ig = 0; ig < 2; ig++)
        #pragma unroll
        for (int rg = 0; rg < 4; rg++) mt[ig][rg] = NEG;

      #pragma unroll
      for (int nb = 0; nb < 8; nb++) {
        if (nb < nbmax) {
          bf16x8 bk[4];
          #pragma unroll
          for (int ks = 0; ks < 4; ks++)
            bk[ks] = *(const bf16x8*)(kvls + (nb * 16 + lid) * 128 + (((ks * 4 + quad) ^ lid) << 3));
          f32x4 s0, s1;
          s0[0]=0.f;s0[1]=0.f;s0[2]=0.f;s0[3]=0.f;
          s1[0]=0.f;s1[1]=0.f;s1[2]=0.f;s1[3]=0.f;
          #pragma unroll
          for (int ks = 0; ks < 4; ks++) {
            s0 = __builtin_amdgcn_mfma_f32_16x16x32_bf16(qf[0][ks], bk[ks], s0, 0, 0, 0);
            s1 = __builtin_amdgcn_mfma_f32_16x16x32_bf16(qf[1][ks], bk[ks], s1, 0, 0, 0);
          }
          const int jl = j0 + nb * 16 + lid;
          const float sj = slope2 * (float)jl;
          #pragma unroll
          for (int rg = 0; rg < 4; rg++) {
            const int row0r = rw + quad * 4 + rg;
            float e0 = fmaf(s0[rg], scale2, sj) - srow2[0][rg];
            e0 = (jl <= row0r) ? e0 : NEG;
            pvv[0][nb][rg] = e0;
            mt[0][rg] = fmaxf(mt[0][rg], e0);
            float e1 = fmaf(s1[rg], scale2, sj) - srow2[1][rg];
            e1 = (jl <= row0r + 16) ? e1 : NEG;
            pvv[1][nb][rg] = e1;
            mt[1][rg] = fmaxf(mt[1][rg], e1);
          }
        }
      }

      float alpha[2][4];
      #pragma unroll
      for (int ig = 0; ig < 2; ig++)
        #pragma unroll
        for (int rg = 0; rg < 4; rg++) {
          float m = mt[ig][rg];
          m = fmaxf(m, __shfl_xor(m, 1));
          m = fmaxf(m, __shfl_xor(m, 2));
          m = fmaxf(m, __shfl_xor(m, 4));
          m = fmaxf(m, __shfl_xor(m, 8));
          float mn = fmaxf(m2[ig][rg], m);
          alpha[ig][rg] = fast_exp2(m2[ig][rg] - mn);
          m2[ig][rg] = mn;
        }

      float rs[2][4];
      #pragma unroll
      for (int ig = 0; ig < 2; ig++)
        #pragma unroll
        for (int rg = 0; rg < 4; rg++) rs[ig][rg] = 0.f;
      #pragma unroll
      for (int nb = 0; nb < 8; nb++) {
        if (nb < nbmax) {
          #pragma unroll
          for (int ig = 0; ig < 2; ig++)
            #pragma unroll
            for (int rg = 0; rg < 4; rg++) {
              float p = fast_exp2(pvv[ig][nb][rg] - m2[ig][rg]);
              rs[ig][rg] += p;
              plds[wave][ig * 16 + quad * 4 + rg][nb * 16 + lid] = f2bf(p);
            }
        }
      }
      if (nbmax & 1) {                               // zero pad strip so PV k-chunks read zeros
        #pragma unroll
        for (int ig = 0; ig < 2; ig++)
          #pragma unroll
          for (int rg = 0; rg < 4; rg++)
            plds[wave][ig * 16 + quad * 4 + rg][nbmax * 16 + lid] = 0;
      }

      #pragma unroll
      for (int ig = 0; ig < 2; ig++)
        #pragma unroll
        for (int rg = 0; rg < 4; rg++) {
          float r = rs[ig][rg];
          r += __shfl_xor(r, 1);
          r += __shfl_xor(r, 2);
          r += __shfl_xor(r, 4);
          r += __shfl_xor(r, 8);
          l[ig][rg] = l[ig][rg] * alpha[ig][rg] + r;
        }
      #pragma unroll
      for (int ig = 0; ig < 2; ig++)
        #pragma unroll
        for (int nd = 0; nd < 8; nd++)
          #pragma unroll
          for (int rg = 0; rg < 4; rg++) o[ig][nd][rg] *= alpha[ig][rg];

      asm volatile("s_waitcnt lgkmcnt(0)" ::: "memory");   // plds writes visible to own wave's reads
      #pragma unroll
      for (int ks2 = 0; ks2 < 4; ks2++) {
        if (ks2 < ks2max) {
          bf16x8 pa0 = *(const bf16x8*)&plds[wave][lid][ks2 * 32 + quad * 8];
          bf16x8 pa1 = *(const bf16x8*)&plds[wave][16 + lid][ks2 * 32 + quad * 8];
          #pragma unroll
          for (int nd = 0; nd < 8; nd++) {
            bf16x8 bv = *(const bf16x8*)(kvtls + (nd * 16 + lid) * 128 + (((ks2 * 4 + quad) ^ lid) << 3));
            o[0][nd] = __builtin_amdgcn_mfma_f32_16x16x32_bf16(pa0, bv, o[0][nd], 0, 0, 0);
            o[1][nd] = __builtin_amdgcn_mfma_f32_16x16x32_bf16(pa1, bv, o[1][nd], 0, 0, 0);
          }
        }
      }
    } // jt

    #pragma unroll
    for (int ig = 0; ig < 2; ig++) {
      float inv[4];
      #pragma unroll
      for (int rg = 0; rg < 4; rg++) inv[rg] = 1.0f / l[ig][rg];
      #pragma unroll
      for (int nd = 0; nd < 8; nd++)
        #pragma unroll
        for (int rg = 0; rg < 4; rg++) {
          int row = rw + ig * 16 + quad * 4 + rg;
          attnws[(size_t)(b * SEQ + row) * DIMM + h * DH + nd * 16 + lid] =
              f2bf(o[ig][nd][rg] * inv[rg]);
        }
    }
  } // tt
}

// ---------------- launcher ----------------
extern "C" void kernel_launch(void* const* d_in, const int* in_sizes, int n_in,
                              void* d_out, int out_size, void* d_ws, size_t ws_size,
                              hipStream_t stream) {
  (void)in_sizes; (void)n_in; (void)out_size; (void)ws_size;
  const float* x     = (const float*)d_in[0];
  const float* g     = (const float*)d_in[1];
  const float* w_qkv = (const float*)d_in[2];
  const float* w_ao  = (const float*)d_in[3];
  const float* w_ff1 = (const float*)d_in[4];
  const float* w_ff2 = (const float*)d_in[5];
  float* out = (float*)d_out;

  u16* ws = (u16*)d_ws;
  u16* xn     = ws;                   // 4096x2048
  u16* wTqkv  = xn     + 8388608;     // 2176x2048
  u16* wTattn = wTqkv  + 4456448;     // 2048x2048
  u16* wTff1  = wTattn + 4194304;     // 16384x2048
  u16* wTff2  = wTff1  + 33554432;    // 2048x8192
  u16* ffin   = wTff2  + 16777216;    // 4096x8192
  u16* qws    = ffin   + 33554432;    // 4096x2048
  u16* kvws   = qws    + 8388608;     // 4096x128
  u16* kvtws  = kvws   + 524288;      // 2 x (128x2048)
  u16* attnws = kvtws  + 524288;      // 4096x2048

  transpose_to_bf16<float><<<dim3(QKVN/64, DIMM/64), 256, 0, stream>>>(w_qkv, wTqkv, DIMM, QKVN);
  transpose_to_bf16<float><<<dim3(DIMM/64, DIMM/64), 256, 0, stream>>>(w_ao, wTattn, DIMM, DIMM);
  transpose_to_bf16<float><<<dim3((2*FFH)/64, DIMM/64), 256, 0, stream>>>(w_ff1, wTff1, DIMM, 2*FFH);
  transpose_to_bf16<float><<<dim3(DIMM/64, FFH/64), 256, 0, stream>>>(w_ff2, wTff2, FFH, DIMM);

  rmsnorm_k<<<ROWS, 256, 0, stream>>>(x, g, xn);

  gemm_bf16<0><<<dim3(QKVN/128, ROWS/128), 256, 0, stream>>>(xn, wTqkv, DIMM, nullptr, qws, kvws);

  transpose_to_bf16<u16><<<dim3(DH/64, SEQ/64), 256, 0, stream>>>(kvws, kvtws, SEQ, DH);
  transpose_to_bf16<u16><<<dim3(DH/64, SEQ/64), 256, 0, stream>>>(kvws + (size_t)SEQ*DH, kvtws + (size_t)DH*SEQ, SEQ, DH);

  attn_k2<<<dim3(8, NH*BATCH), 256, 0, stream>>>(qws, kvws, kvtws, attnws);

  gemm_ff1_swiglu<<<dim3(FFH/64, ROWS/128), 256, 0, stream>>>(xn, wTff1, ffin);
  gemm_bf16<2><<<dim3(DIMM/128, ROWS/128), 256, 0, stream>>>(ffin, wTff2, FFH, out, nullptr, nullptr);

  gemm_bf16<3><<<dim3(DIMM/128, ROWS/128), 256, 0, stream>>>(attnws, wTattn, DIMM, out, nullptr, nullptr);
}